// Round 6
// baseline (329.862 us; speedup 1.0000x reference)
//
#include <hip/hip_runtime.h>
#include <hip/hip_bf16.h>
#include <math.h>

#define BATCH   4096
#define DIM     1024
#define NGROUPS 1024
#define INV_T   10.0f
#define RANK_W  0.1f
#define SCORE_W 0.01f

#define BI 128       // q rows per block
#define BJ 256       // a rows per block
#define KC 32        // k per stage
#define NT (DIM/KC)  // 32 K-steps
#define NFRAG_Q (BI/16)          // 8
#define NFRAG   (BI/16 + BJ/16)  // 24 fragments per stage
#define NSTG    3                // fragments staged per wave (24 / 8 waves)
#define FRAG_ELEMS 512           // 16 rows x 32 k bf16
#define NJB     (BATCH/BJ)       // 16 column blocks per row band

typedef float  floatx4 __attribute__((ext_vector_type(4)));
typedef __bf16 bf16x8  __attribute__((ext_vector_type(8)));
typedef __bf16 bf16x4  __attribute__((ext_vector_type(4)));

// async 16B/lane global->LDS: LDS dest is wave-uniform base + lane*16
#define ASYNC_COPY16(gptr, lptr)                                              \
    __builtin_amdgcn_global_load_lds(                                         \
        (const __attribute__((address_space(1))) void*)(gptr),                \
        (__attribute__((address_space(3))) void*)(lptr), 16, 0, 0)

// ---------------------------------------------------------------------------
// Kernel 1: prep. Blocks [0,1024): per-group weights (+ block 0 zeroes the
// out scalars and the split-K fixup counters). Blocks [1024,2048):
// fp32 -> bf16 conversion of Q and A into ws.
// ---------------------------------------------------------------------------
__global__ __launch_bounds__(256) void prep_kernel(
    const float* __restrict__ Q, const float* __restrict__ A,
    __bf16* __restrict__ Qb, __bf16* __restrict__ Ab,
    const int* __restrict__ qid, const float* __restrict__ ranks,
    const float* __restrict__ scores, float* __restrict__ w,
    float* __restrict__ out, int* __restrict__ cnt)
{
    const int tid = threadIdx.x;

    if (blockIdx.x >= NGROUPS) {
        const int cid = blockIdx.x - NGROUPS;          // 0..1023
        const int n4  = BATCH * DIM / 4;               // 1M float4 per matrix
        for (int i = cid * 256 + tid; i < n4; i += 1024 * 256) {
            float4 v = ((const float4*)Q)[i];
            bf16x4 b;
            b[0] = (__bf16)v.x; b[1] = (__bf16)v.y;
            b[2] = (__bf16)v.z; b[3] = (__bf16)v.w;
            ((bf16x4*)Qb)[i] = b;
            v = ((const float4*)A)[i];
            b[0] = (__bf16)v.x; b[1] = (__bf16)v.y;
            b[2] = (__bf16)v.z; b[3] = (__bf16)v.w;
            ((bf16x4*)Ab)[i] = b;
        }
        return;
    }

    // ---- group-weight part: one block (256 threads) per group ----
    const int g = blockIdx.x, lane = tid & 63, wv = tid >> 6;

    if (g == 0) {                       // zero accumulators + fixup counters
        if (tid < 2)  out[tid] = 0.f;
        if (tid < BATCH / BI) cnt[tid] = 0;
    }

    __shared__ float rmax[4], rmin[4], rsum[4];

    float gmax = -INFINITY, gmin = INFINITY;
    for (int j = tid; j < BATCH; j += 256) {
        if (qid[j] == g) {
            float s = scores[j];
            gmax = fmaxf(gmax, s);
            gmin = fminf(gmin, s);
        }
    }
    #pragma unroll
    for (int d = 1; d < 64; d <<= 1) {
        gmax = fmaxf(gmax, __shfl_xor(gmax, d, 64));
        gmin = fminf(gmin, __shfl_xor(gmin, d, 64));
    }
    if (lane == 0) { rmax[wv] = gmax; rmin[wv] = gmin; }
    __syncthreads();
    gmax = fmaxf(fmaxf(rmax[0], rmax[1]), fmaxf(rmax[2], rmax[3]));
    gmin = fminf(fminf(rmin[0], rmin[1]), fminf(rmin[2], rmin[3]));
    const float denom     = gmax - gmin;
    const float inv_denom = (denom > 0.f) ? 1.f / denom : 0.f;

    float lsum = 0.f;
    for (int j = tid; j < BATCH; j += 256) {
        if (qid[j] == g) {
            float norm = (scores[j] - gmin) * inv_denom;
            float u = __expf(-RANK_W * ranks[j] + SCORE_W * norm);
            w[j] = u;             // unnormalized; this thread owns j
            lsum += u;
        }
    }
    #pragma unroll
    for (int d = 1; d < 64; d <<= 1) lsum += __shfl_xor(lsum, d, 64);
    if (lane == 0) rsum[wv] = lsum;
    __syncthreads();
    const float wsum = rsum[0] + rsum[1] + rsum[2] + rsum[3];
    const float inv  = (wsum > 0.f) ? 1.f / wsum : 0.f;
    for (int j = tid; j < BATCH; j += 256) {
        if (qid[j] == g) w[j] *= inv;
    }
}

// ---------------------------------------------------------------------------
// Kernel 2: fused sim = (Qb Ab^T)/T with online per-row (max, sumexp,
// weighted-sum, argmax) partials per 64-col slice, PLUS split-K style fixup:
// the last jb-block to finish a 128-row band merges all 64 slice partials
// for its band and atomically accumulates loss/acc into out[0..1].
// Matmul core identical to the verified R5 kernel (73.5 us):
// 128x256 tile, 8 waves of 64x64, fragment-major LDS, 3 buffers,
// 1 barrier/K-step, counted vmcnt(3).
// ---------------------------------------------------------------------------
__global__ __launch_bounds__(512, 4) void fused_simloss_kernel(
    const __bf16* __restrict__ Qb, const __bf16* __restrict__ Ab,
    const int* __restrict__ qid, const float* __restrict__ w,
    float* __restrict__ Pm, float* __restrict__ Pl, float* __restrict__ Ps,
    float* __restrict__ Pbv, int* __restrict__ Pbi,
    int* __restrict__ cnt, float* __restrict__ out)
{
    __shared__ __bf16 sbuf[3][NFRAG * FRAG_ELEMS];   // 3 x 24 KB = 72 KB
    __shared__ int last_flag;

    const int jb = blockIdx.x, ib = blockIdx.y;
    const int i0 = ib * BI, j0 = jb * BJ;
    const int tid = threadIdx.x, wid = tid >> 6, lane = tid & 63;
    const int wm = wid >> 2, wn = wid & 3;      // 2x4 wave grid, 64x64 tiles
    const int quad = lane >> 4, l16 = lane & 15;

    floatx4 acc[4][4];
    #pragma unroll
    for (int m = 0; m < 4; ++m)
        #pragma unroll
        for (int n = 0; n < 4; ++n)
            #pragma unroll
            for (int c = 0; c < 4; ++c) acc[m][n][c] = 0.f;

    // staging: wave `wid` owns fragments f = wid*3 .. wid*3+2
    const int lr = lane & 15;
    const int lk = (lane >> 4) * 8;
    const __bf16* src[NSTG];
    #pragma unroll
    for (int c = 0; c < NSTG; ++c) {
        const int f = wid * NSTG + c;
        src[c] = (f < NFRAG_Q)
               ? Qb + (size_t)(i0 + f * 16 + lr) * DIM + lk
               : Ab + (size_t)(j0 + (f - NFRAG_Q) * 16 + lr) * DIM + lk;
    }

    #define STAGE(bufptr, k0)                                                 \
        do {                                                                  \
            _Pragma("unroll")                                                 \
            for (int c = 0; c < NSTG; ++c)                                    \
                ASYNC_COPY16(src[c] + (k0),                                   \
                             (__bf16*)(bufptr) + (wid * NSTG + c) * FRAG_ELEMS); \
        } while (0)

    // rotating buffer pointers (named vars, never runtime-indexed -> regs)
    __bf16* bprev = sbuf[2];   // free at t=0 (prologue stages only 0,1)
    __bf16* bcur  = sbuf[0];
    __bf16* bnext = sbuf[1];

    STAGE(bcur, 0);            // tile 0 -> buf0
    STAGE(bnext, KC);          // tile 1 -> buf1

    for (int t = 0; t < NT; ++t) {
        // single barrier per K-step; counted vmcnt: tile t landed,
        // tile t+1's 3 copies stay in flight.
        if (t < NT - 1) asm volatile("s_waitcnt vmcnt(3)\n\ts_barrier" ::: "memory");
        else            asm volatile("s_waitcnt vmcnt(0)\n\ts_barrier" ::: "memory");

        // STAGE first (T3 recipe): tile t+2 into the buffer read at t-1
        if (t + 2 < NT) STAGE(bprev, (t + 2) * KC);

        const __bf16* cur = bcur;
        bf16x8 qf[4], af[4];
        #pragma unroll
        for (int mf = 0; mf < 4; ++mf)
            qf[mf] = *(const bf16x8*)&cur[(wm * 4 + mf) * FRAG_ELEMS + lane * 8];
        #pragma unroll
        for (int nf = 0; nf < 4; ++nf)
            af[nf] = *(const bf16x8*)&cur[(NFRAG_Q + wn * 4 + nf) * FRAG_ELEMS + lane * 8];

        __builtin_amdgcn_s_setprio(1);
        #pragma unroll
        for (int nf = 0; nf < 4; ++nf)
            #pragma unroll
            for (int mf = 0; mf < 4; ++mf)
                acc[mf][nf] = __builtin_amdgcn_mfma_f32_16x16x32_bf16(
                    qf[mf], af[nf], acc[mf][nf], 0, 0, 0);
        __builtin_amdgcn_s_setprio(0);

        // rotate: {prev,cur,next} <- {cur,next,prev}
        __bf16* tmp = bprev;
        bprev = bcur; bcur = bnext; bnext = tmp;
    }
    #undef STAGE

    // ---- epilogue: (m, l, s, argmax) per row within this wave's 64-col slice
    int cq[4]; float cw[4];
    #pragma unroll
    for (int n = 0; n < 4; ++n) {
        int col = j0 + wn * 64 + n * 16 + l16;
        cq[n] = qid[col];
        cw[n] = w[col];
    }
    const int slice = jb * 4 + wn;             // 0..63

    #pragma unroll
    for (int m = 0; m < 4; ++m) {
        #pragma unroll
        for (int reg = 0; reg < 4; ++reg) {
            const int row = i0 + wm * 64 + m * 16 + quad * 4 + reg;
            const int rq  = qid[row];

            float v[4];
            #pragma unroll
            for (int n = 0; n < 4; ++n) v[n] = acc[m][n][reg] * INV_T;

            // pass 1: slice-wide max
            float pm = fmaxf(fmaxf(v[0], v[1]), fmaxf(v[2], v[3]));
            #pragma unroll
            for (int d = 1; d < 16; d <<= 1)
                pm = fmaxf(pm, __shfl_xor(pm, d, 64));

            // pass 2: local sums against the global max + local argmax
            float ll = __expf(v[0] - pm) + __expf(v[1] - pm) +
                       __expf(v[2] - pm) + __expf(v[3] - pm);
            float ls = 0.f;
            #pragma unroll
            for (int n = 0; n < 4; ++n) ls += (cq[n] == rq) ? cw[n] * v[n] : 0.f;

            float bv = v[0];
            int   bi = j0 + wn * 64 + l16;
            #pragma unroll
            for (int n = 1; n < 4; ++n) {
                int c = j0 + wn * 64 + n * 16 + l16;
                if (v[n] > bv) { bv = v[n]; bi = c; }
            }

            // combined sum + argmax reduce over 16 lanes
            #pragma unroll
            for (int d = 1; d < 16; d <<= 1) {
                ll += __shfl_xor(ll, d, 64);
                ls += __shfl_xor(ls, d, 64);
                float obv = __shfl_xor(bv, d, 64);
                int   obi = __shfl_xor(bi, d, 64);
                if (obv > bv || (obv == bv && obi < bi)) { bv = obv; bi = obi; }
            }
            if (l16 == 0) {
                int idx = row * 64 + slice;
                Pm[idx] = pm; Pl[idx] = ll; Ps[idx] = ls;
                Pbv[idx] = bv; Pbi[idx] = bi;
            }
        }
    }

    // ---- split-K fixup: last jb-block of this row band merges all slices.
    // release: every thread fences its partial stores, then block-wide sync,
    // then one thread bumps the band counter (device-scope atomic).
    __threadfence();
    __syncthreads();
    if (tid == 0) {
        int prev = atomicAdd(&cnt[ib], 1);
        last_flag = (prev == NJB - 1) ? 1 : 0;
    }
    __syncthreads();
    if (!last_flag) return;

    __threadfence();   // acquire: order partial reads after flag observation

    // each wave merges rows rr = wid, wid+8, ... (16 rows per wave)
    float s1 = 0.f, s2 = 0.f;
    for (int rr = wid; rr < BI; rr += 8) {
        const int row = i0 + rr;
        const int idx = row * 64 + lane;
        float m = Pm[idx], l = Pl[idx], s = Ps[idx], bv = Pbv[idx];
        int   bi = Pbi[idx];
        #pragma unroll
        for (int d = 1; d < 64; d <<= 1) {
            float om  = __shfl_xor(m, d, 64);
            float ol  = __shfl_xor(l, d, 64);
            float os  = __shfl_xor(s, d, 64);
            float obv = __shfl_xor(bv, d, 64);
            int   obi = __shfl_xor(bi, d, 64);
            float nm = fmaxf(m, om);
            l = l * __expf(m - nm) + ol * __expf(om - nm);
            m = nm;
            s += os;
            if (obv > bv || (obv == bv && obi < bi)) { bv = obv; bi = obi; }
        }
        if (lane == 0) {
            s1 += (m + logf(l)) - s;
            s2 += (qid[bi] == qid[row]) ? 1.f : 0.f;
        }
    }
    if (lane == 0) {
        atomicAdd(&out[0], s1 * (1.f / (float)BATCH));
        atomicAdd(&out[1], s2 * (1.f / (float)BATCH));
    }
}

// ---------------------------------------------------------------------------
extern "C" void kernel_launch(void* const* d_in, const int* in_sizes, int n_in,
                              void* d_out, int out_size, void* d_ws, size_t ws_size,
                              hipStream_t stream)
{
    const float* Q      = (const float*)d_in[0];
    const float* A      = (const float*)d_in[1];
    const int*   qid    = (const int*)d_in[2];
    const float* ranks  = (const float*)d_in[3];
    const float* scores = (const float*)d_in[4];
    float* out = (float*)d_out;

    // ws layout: Qb[4M bf16]=8MB | Ab[4M bf16]=8MB | w[4096] |
    //            Pm,Pl,Ps,Pbv[262144] | Pbi[262144] | cnt[32]
    __bf16* Qb = (__bf16*)d_ws;
    __bf16* Ab = Qb + (size_t)BATCH * DIM;
    float* w   = (float*)(Ab + (size_t)BATCH * DIM);
    float* Pm  = w + BATCH;
    float* Pl  = Pm + BATCH * 64;
    float* Ps  = Pl + BATCH * 64;
    float* Pbv = Ps + BATCH * 64;
    int*   Pbi = (int*)(Pbv + BATCH * 64);
    int*   cnt = Pbi + BATCH * 64;

    prep_kernel<<<2048, 256, 0, stream>>>(Q, A, Qb, Ab, qid, ranks, scores, w,
                                          out, cnt);

    dim3 grid(BATCH / BJ, BATCH / BI);  // 16 x 32 = 512 blocks
    fused_simloss_kernel<<<grid, 512, 0, stream>>>(Qb, Ab, qid, w,
                                                   Pm, Pl, Ps, Pbv, Pbi,
                                                   cnt, out);
}

// Round 7
// 176.238 us; speedup vs baseline: 1.8717x; 1.8717x over previous
//
#include <hip/hip_runtime.h>
#include <hip/hip_bf16.h>
#include <math.h>

#define BATCH   4096
#define DIM     1024
#define NGROUPS 1024
#define INV_T   10.0f
#define RANK_W  0.1f
#define SCORE_W 0.01f

#define BI 128       // q rows per block
#define BJ 256       // a rows per block
#define KC 32        // k per stage
#define NT (DIM/KC)  // 32 K-steps
#define NFRAG_Q (BI/16)          // 8
#define NFRAG   (BI/16 + BJ/16)  // 24 fragments per stage
#define NSTG    3                // fragments staged per wave (24 / 8 waves)
#define FRAG_ELEMS 512           // 16 rows x 32 k bf16

typedef float  floatx4 __attribute__((ext_vector_type(4)));
typedef __bf16 bf16x8  __attribute__((ext_vector_type(8)));
typedef __bf16 bf16x4  __attribute__((ext_vector_type(4)));

// async 16B/lane global->LDS: LDS dest is wave-uniform base + lane*16
#define ASYNC_COPY16(gptr, lptr)                                              \
    __builtin_amdgcn_global_load_lds(                                         \
        (const __attribute__((address_space(1))) void*)(gptr),                \
        (__attribute__((address_space(3))) void*)(lptr), 16, 0, 0)

// ---------------------------------------------------------------------------
// Kernel 1: prep.
// Blocks [0,1024): fp32 -> bf16 conversion of Q and A (block 0 also zeroes
// the output accumulators). Block 1024: the entire group-weight computation,
// LDS-resident (one pass over qid/scores/ranks instead of 1024 x 3 passes).
// ---------------------------------------------------------------------------
__global__ __launch_bounds__(256) void prep_kernel(
    const float* __restrict__ Q, const float* __restrict__ A,
    __bf16* __restrict__ Qb, __bf16* __restrict__ Ab,
    const int* __restrict__ qid, const float* __restrict__ ranks,
    const float* __restrict__ scores, float* __restrict__ w,
    float* __restrict__ out)
{
    const int tid = threadIdx.x;

    if (blockIdx.x < 1024) {
        if (blockIdx.x == 0 && tid < 2) out[tid] = 0.f;   // zero loss/acc accums
        const int cid = blockIdx.x;                 // 0..1023
        const int n4  = BATCH * DIM / 4;            // 1M float4 per matrix
        for (int i = cid * 256 + tid; i < n4; i += 1024 * 256) {
            float4 v = ((const float4*)Q)[i];
            bf16x4 b;
            b[0] = (__bf16)v.x; b[1] = (__bf16)v.y;
            b[2] = (__bf16)v.z; b[3] = (__bf16)v.w;
            ((bf16x4*)Qb)[i] = b;
            v = ((const float4*)A)[i];
            b[0] = (__bf16)v.x; b[1] = (__bf16)v.y;
            b[2] = (__bf16)v.z; b[3] = (__bf16)v.w;
            ((bf16x4*)Ab)[i] = b;
        }
        return;
    }

    // ---- single weight block: everything in LDS ----
    // scores/ranks >= 0, so float bit patterns are order-preserving as ints.
    __shared__ int   qidS[BATCH];      // 16 KB
    __shared__ float scoS[BATCH];      // 16 KB
    __shared__ int   gmaxS[NGROUPS];   // 4 KB (float bits)
    __shared__ int   gminS[NGROUPS];   // 4 KB (float bits)
    __shared__ float wsumS[NGROUPS];   // 4 KB

    #pragma unroll
    for (int k = 0; k < BATCH / 256; ++k) {
        const int j = tid + k * 256;
        qidS[j] = qid[j];
        scoS[j] = scores[j];
    }
    #pragma unroll
    for (int k = 0; k < NGROUPS / 256; ++k) {
        const int g = tid + k * 256;
        gmaxS[g] = 0;              // bits(0.0f) <= bits of any nonneg score
        gminS[g] = 0x7F800000;     // bits(+inf)
        wsumS[g] = 0.f;
    }
    __syncthreads();

    #pragma unroll
    for (int k = 0; k < BATCH / 256; ++k) {
        const int j = tid + k * 256;
        const int g = qidS[j];
        const int sb = __float_as_int(scoS[j]);
        atomicMax(&gmaxS[g], sb);
        atomicMin(&gminS[g], sb);
    }
    __syncthreads();

    float u[BATCH / 256];
    #pragma unroll
    for (int k = 0; k < BATCH / 256; ++k) {
        const int j = tid + k * 256;
        const int g = qidS[j];
        const float gmax = __int_as_float(gmaxS[g]);
        const float gmin = __int_as_float(gminS[g]);
        const float d    = gmax - gmin;
        const float invd = (d > 0.f) ? 1.f / d : 0.f;
        const float norm = (scoS[j] - gmin) * invd;
        u[k] = __expf(-RANK_W * ranks[j] + SCORE_W * norm);
        atomicAdd(&wsumS[g], u[k]);
    }
    __syncthreads();

    #pragma unroll
    for (int k = 0; k < BATCH / 256; ++k) {
        const int j = tid + k * 256;
        w[j] = u[k] / wsumS[qidS[j]];   // wsum > 0: group of j is nonempty
    }
}

// ---------------------------------------------------------------------------
// Kernel 2: fused sim = (Qb Ab^T)/T with online per-row (max, sumexp,
// weighted-sum, argmax) partials per 64-col slice.  (Verified R5 core.)
// 128x256 block tile, 8 waves of 64x64, fragment-major LDS (0 conflicts).
// ONE barrier per K-step, 3 LDS buffers, counted vmcnt(3).
// ---------------------------------------------------------------------------
__global__ __launch_bounds__(512, 4) void fused_simloss_kernel(
    const __bf16* __restrict__ Qb, const __bf16* __restrict__ Ab,
    const int* __restrict__ qid, const float* __restrict__ w,
    float* __restrict__ Pm, float* __restrict__ Pl, float* __restrict__ Ps,
    float* __restrict__ Pbv, int* __restrict__ Pbi)
{
    __shared__ __bf16 sbuf[3][NFRAG * FRAG_ELEMS];   // 3 x 24 KB = 72 KB

    const int jb = blockIdx.x, ib = blockIdx.y;
    const int i0 = ib * BI, j0 = jb * BJ;
    const int tid = threadIdx.x, wid = tid >> 6, lane = tid & 63;
    const int wm = wid >> 2, wn = wid & 3;      // 2x4 wave grid, 64x64 tiles
    const int quad = lane >> 4, l16 = lane & 15;

    floatx4 acc[4][4];
    #pragma unroll
    for (int m = 0; m < 4; ++m)
        #pragma unroll
        for (int n = 0; n < 4; ++n)
            #pragma unroll
            for (int c = 0; c < 4; ++c) acc[m][n][c] = 0.f;

    // staging: wave `wid` owns fragments f = wid*3 .. wid*3+2
    const int lr = lane & 15;
    const int lk = (lane >> 4) * 8;
    const __bf16* src[NSTG];
    #pragma unroll
    for (int c = 0; c < NSTG; ++c) {
        const int f = wid * NSTG + c;
        src[c] = (f < NFRAG_Q)
               ? Qb + (size_t)(i0 + f * 16 + lr) * DIM + lk
               : Ab + (size_t)(j0 + (f - NFRAG_Q) * 16 + lr) * DIM + lk;
    }

    #define STAGE(bufptr, k0)                                                 \
        do {                                                                  \
            _Pragma("unroll")                                                 \
            for (int c = 0; c < NSTG; ++c)                                    \
                ASYNC_COPY16(src[c] + (k0),                                   \
                             (__bf16*)(bufptr) + (wid * NSTG + c) * FRAG_ELEMS); \
        } while (0)

    // rotating buffer pointers (named vars, never runtime-indexed -> regs)
    __bf16* bprev = sbuf[2];   // free at t=0 (prologue stages only 0,1)
    __bf16* bcur  = sbuf[0];
    __bf16* bnext = sbuf[1];

    STAGE(bcur, 0);            // tile 0 -> buf0
    STAGE(bnext, KC);          // tile 1 -> buf1

    for (int t = 0; t < NT; ++t) {
        // single barrier per K-step; counted vmcnt: tile t landed,
        // tile t+1's 3 copies stay in flight.
        if (t < NT - 1) asm volatile("s_waitcnt vmcnt(3)\n\ts_barrier" ::: "memory");
        else            asm volatile("s_waitcnt vmcnt(0)\n\ts_barrier" ::: "memory");

        // STAGE first (T3 recipe): tile t+2 into the buffer read at t-1
        if (t + 2 < NT) STAGE(bprev, (t + 2) * KC);

        const __bf16* cur = bcur;
        bf16x8 qf[4], af[4];
        #pragma unroll
        for (int mf = 0; mf < 4; ++mf)
            qf[mf] = *(const bf16x8*)&cur[(wm * 4 + mf) * FRAG_ELEMS + lane * 8];
        #pragma unroll
        for (int nf = 0; nf < 4; ++nf)
            af[nf] = *(const bf16x8*)&cur[(NFRAG_Q + wn * 4 + nf) * FRAG_ELEMS + lane * 8];

        __builtin_amdgcn_s_setprio(1);
        #pragma unroll
        for (int nf = 0; nf < 4; ++nf)
            #pragma unroll
            for (int mf = 0; mf < 4; ++mf)
                acc[mf][nf] = __builtin_amdgcn_mfma_f32_16x16x32_bf16(
                    qf[mf], af[nf], acc[mf][nf], 0, 0, 0);
        __builtin_amdgcn_s_setprio(0);

        // rotate: {prev,cur,next} <- {cur,next,prev}
        __bf16* tmp = bprev;
        bprev = bcur; bcur = bnext; bnext = tmp;
    }
    #undef STAGE

    // ---- epilogue: (m, l, s, argmax) per row within this wave's 64-col slice
    int cq[4]; float cw[4];
    #pragma unroll
    for (int n = 0; n < 4; ++n) {
        int col = j0 + wn * 64 + n * 16 + l16;
        cq[n] = qid[col];
        cw[n] = w[col];
    }
    const int slice = jb * 4 + wn;             // 0..63

    #pragma unroll
    for (int m = 0; m < 4; ++m) {
        #pragma unroll
        for (int reg = 0; reg < 4; ++reg) {
            const int row = i0 + wm * 64 + m * 16 + quad * 4 + reg;
            const int rq  = qid[row];

            float v[4];
            #pragma unroll
            for (int n = 0; n < 4; ++n) v[n] = acc[m][n][reg] * INV_T;

            // pass 1: slice-wide max
            float pm = fmaxf(fmaxf(v[0], v[1]), fmaxf(v[2], v[3]));
            #pragma unroll
            for (int d = 1; d < 16; d <<= 1)
                pm = fmaxf(pm, __shfl_xor(pm, d, 64));

            // pass 2: local sums against the global max + local argmax
            float ll = __expf(v[0] - pm) + __expf(v[1] - pm) +
                       __expf(v[2] - pm) + __expf(v[3] - pm);
            float ls = 0.f;
            #pragma unroll
            for (int n = 0; n < 4; ++n) ls += (cq[n] == rq) ? cw[n] * v[n] : 0.f;

            float bv = v[0];
            int   bi = j0 + wn * 64 + l16;
            #pragma unroll
            for (int n = 1; n < 4; ++n) {
                int c = j0 + wn * 64 + n * 16 + l16;
                if (v[n] > bv) { bv = v[n]; bi = c; }
            }

            // combined sum + argmax reduce over 16 lanes
            #pragma unroll
            for (int d = 1; d < 16; d <<= 1) {
                ll += __shfl_xor(ll, d, 64);
                ls += __shfl_xor(ls, d, 64);
                float obv = __shfl_xor(bv, d, 64);
                int   obi = __shfl_xor(bi, d, 64);
                if (obv > bv || (obv == bv && obi < bi)) { bv = obv; bi = obi; }
            }
            if (l16 == 0) {
                int idx = row * 64 + slice;
                Pm[idx] = pm; Pl[idx] = ll; Ps[idx] = ls;
                Pbv[idx] = bv; Pbi[idx] = bi;
            }
        }
    }
}

// ---------------------------------------------------------------------------
// Kernel 3: merge 64 slice-partials per row -> loss/acc contributions,
// accumulated directly into out[0..1] (zeroed by prep, stream-ordered).
// No intra-dispatch communication -> no fences needed; atomics are
// device-scope by default.
// ---------------------------------------------------------------------------
__global__ __launch_bounds__(256) void row_reduce_kernel(
    const float* __restrict__ Pm, const float* __restrict__ Pl,
    const float* __restrict__ Ps, const float* __restrict__ Pbv,
    const int* __restrict__ Pbi, const int* __restrict__ qid,
    float* __restrict__ out)
{
    const int wv   = threadIdx.x >> 6;
    const int r    = blockIdx.x * 4 + wv;
    const int lane = threadIdx.x & 63;
    const int idx  = r * 64 + lane;

    float m = Pm[idx], l = Pl[idx], s = Ps[idx], bv = Pbv[idx];
    int   bi = Pbi[idx];

    #pragma unroll
    for (int d = 1; d < 64; d <<= 1) {
        float om  = __shfl_xor(m, d, 64);
        float ol  = __shfl_xor(l, d, 64);
        float os  = __shfl_xor(s, d, 64);
        float obv = __shfl_xor(bv, d, 64);
        int   obi = __shfl_xor(bi, d, 64);
        float nm = fmaxf(m, om);
        l = l * __expf(m - nm) + ol * __expf(om - nm);
        m = nm;
        s += os;
        if (obv > bv || (obv == bv && obi < bi)) { bv = obv; bi = obi; }
    }

    __shared__ float r1[4], r2[4];
    if (lane == 0) {
        r1[wv] = (m + logf(l)) - s;
        r2[wv] = (qid[bi] == qid[r]) ? 1.f : 0.f;
    }
    __syncthreads();
    if (threadIdx.x == 0) {
        float t1 = r1[0] + r1[1] + r1[2] + r1[3];
        float t2 = r2[0] + r2[1] + r2[2] + r2[3];
        atomicAdd(&out[0], t1 * (1.f / (float)BATCH));
        atomicAdd(&out[1], t2 * (1.f / (float)BATCH));
    }
}

// ---------------------------------------------------------------------------
extern "C" void kernel_launch(void* const* d_in, const int* in_sizes, int n_in,
                              void* d_out, int out_size, void* d_ws, size_t ws_size,
                              hipStream_t stream)
{
    const float* Q      = (const float*)d_in[0];
    const float* A      = (const float*)d_in[1];
    const int*   qid    = (const int*)d_in[2];
    const float* ranks  = (const float*)d_in[3];
    const float* scores = (const float*)d_in[4];
    float* out = (float*)d_out;

    // ws layout: Qb[4M bf16]=8MB | Ab[4M bf16]=8MB | w[4096] |
    //            Pm,Pl,Ps,Pbv[262144] | Pbi[262144]
    __bf16* Qb = (__bf16*)d_ws;
    __bf16* Ab = Qb + (size_t)BATCH * DIM;
    float* w   = (float*)(Ab + (size_t)BATCH * DIM);
    float* Pm  = w + BATCH;
    float* Pl  = Pm + BATCH * 64;
    float* Ps  = Pl + BATCH * 64;
    float* Pbv = Ps + BATCH * 64;
    int*   Pbi = (int*)(Pbv + BATCH * 64);

    prep_kernel<<<1025, 256, 0, stream>>>(Q, A, Qb, Ab, qid, ranks, scores, w, out);

    dim3 grid(BATCH / BJ, BATCH / BI);  // 16 x 32 = 512 blocks
    fused_simloss_kernel<<<grid, 512, 0, stream>>>(Qb, Ab, qid, w, Pm, Pl, Ps, Pbv, Pbi);

    row_reduce_kernel<<<BATCH / 4, 256, 0, stream>>>(Pm, Pl, Ps, Pbv, Pbi, qid, out);
}

// Round 9
// 155.774 us; speedup vs baseline: 2.1176x; 1.1314x over previous
//
#include <hip/hip_runtime.h>
#include <hip/hip_bf16.h>
#include <math.h>

#define BATCH   4096
#define DIM     1024
#define NGROUPS 1024
#define INV_T   10.0f
#define RANK_W  0.1f
#define SCORE_W 0.01f

#define BI 128       // q rows per block
#define BJ 256       // a rows per block
#define KC 32        // k per stage
#define NT (DIM/KC)  // 32 K-steps
#define NFRAG_Q (BI/16)          // 8
#define NFRAG   (BI/16 + BJ/16)  // 24 fragments per stage
#define NSTG    3                // fragments staged per wave (24 / 8 waves)
#define FRAG_ELEMS 512           // 16 rows x 32 k bf16

typedef float  floatx4 __attribute__((ext_vector_type(4)));
typedef __bf16 bf16x8  __attribute__((ext_vector_type(8)));
typedef __bf16 bf16x4  __attribute__((ext_vector_type(4)));

// async 16B/lane global->LDS: LDS dest is wave-uniform base + lane*16
#define ASYNC_COPY16(gptr, lptr)                                              \
    __builtin_amdgcn_global_load_lds(                                         \
        (const __attribute__((address_space(1))) void*)(gptr),                \
        (__attribute__((address_space(3))) void*)(lptr), 16, 0, 0)

// ---------------------------------------------------------------------------
// Kernel 1: prep.
// Block 0: the entire group-weight computation, LDS-resident (starts first,
// hides under the conversion blocks). Also zeroes out[0..1].
// Blocks [1,1024]: fp32 -> bf16 conversion of Q and A into ws.
// ---------------------------------------------------------------------------
__global__ __launch_bounds__(256) void prep_kernel(
    const float* __restrict__ Q, const float* __restrict__ A,
    __bf16* __restrict__ Qb, __bf16* __restrict__ Ab,
    const int* __restrict__ qid, const float* __restrict__ ranks,
    const float* __restrict__ scores, float* __restrict__ w,
    float* __restrict__ out)
{
    const int tid = threadIdx.x;

    if (blockIdx.x > 0) {
        const int cid = blockIdx.x - 1;             // 0..1023
        const int n4  = BATCH * DIM / 4;            // 1M float4 per matrix
        for (int i = cid * 256 + tid; i < n4; i += 1024 * 256) {
            float4 v = ((const float4*)Q)[i];
            bf16x4 b;
            b[0] = (__bf16)v.x; b[1] = (__bf16)v.y;
            b[2] = (__bf16)v.z; b[3] = (__bf16)v.w;
            ((bf16x4*)Qb)[i] = b;
            v = ((const float4*)A)[i];
            b[0] = (__bf16)v.x; b[1] = (__bf16)v.y;
            b[2] = (__bf16)v.z; b[3] = (__bf16)v.w;
            ((bf16x4*)Ab)[i] = b;
        }
        return;
    }

    // ---- single weight block (blockIdx 0): everything in LDS ----
    // scores >= 0, so float bit patterns are order-preserving as ints.
    if (tid < 2) out[tid] = 0.f;       // zero loss/acc accumulators

    __shared__ int   qidS[BATCH];      // 16 KB
    __shared__ float scoS[BATCH];      // 16 KB
    __shared__ int   gmaxS[NGROUPS];   // 4 KB (float bits)
    __shared__ int   gminS[NGROUPS];   // 4 KB (float bits)
    __shared__ float wsumS[NGROUPS];   // 4 KB

    #pragma unroll
    for (int k = 0; k < BATCH / 256; ++k) {
        const int j = tid + k * 256;
        qidS[j] = qid[j];
        scoS[j] = scores[j];
    }
    #pragma unroll
    for (int k = 0; k < NGROUPS / 256; ++k) {
        const int g = tid + k * 256;
        gmaxS[g] = 0;              // bits(0.0f) <= bits of any nonneg score
        gminS[g] = 0x7F800000;     // bits(+inf)
        wsumS[g] = 0.f;
    }
    __syncthreads();

    #pragma unroll
    for (int k = 0; k < BATCH / 256; ++k) {
        const int j = tid + k * 256;
        const int g = qidS[j];
        const int sb = __float_as_int(scoS[j]);
        atomicMax(&gmaxS[g], sb);
        atomicMin(&gminS[g], sb);
    }
    __syncthreads();

    float u[BATCH / 256];
    #pragma unroll
    for (int k = 0; k < BATCH / 256; ++k) {
        const int j = tid + k * 256;
        const int g = qidS[j];
        const float gmax = __int_as_float(gmaxS[g]);
        const float gmin = __int_as_float(gminS[g]);
        const float d    = gmax - gmin;
        const float invd = (d > 0.f) ? 1.f / d : 0.f;
        const float norm = (scoS[j] - gmin) * invd;
        u[k] = __expf(-RANK_W * ranks[j] + SCORE_W * norm);
        atomicAdd(&wsumS[g], u[k]);
    }
    __syncthreads();

    #pragma unroll
    for (int k = 0; k < BATCH / 256; ++k) {
        const int j = tid + k * 256;
        w[j] = u[k] / wsumS[qidS[j]];   // wsum > 0: group of j is nonempty
    }
}

// ---------------------------------------------------------------------------
// Kernel 2: fused sim = (Qb Ab^T)/T with online per-row (max, sumexp,
// weighted-sum, argmax) partials per 64-col slice.  (Verified R5/R7 core.)
// 128x256 block tile, 8 waves of 64x64, fragment-major LDS (0 conflicts).
// ONE barrier per K-step, 3 LDS buffers, counted vmcnt(3).
// ---------------------------------------------------------------------------
__global__ __launch_bounds__(512, 4) void fused_simloss_kernel(
    const __bf16* __restrict__ Qb, const __bf16* __restrict__ Ab,
    const int* __restrict__ qid, const float* __restrict__ w,
    float* __restrict__ Pm, float* __restrict__ Pl, float* __restrict__ Ps,
    float* __restrict__ Pbv, int* __restrict__ Pbi)
{
    __shared__ __bf16 sbuf[3][NFRAG * FRAG_ELEMS];   // 3 x 24 KB = 72 KB

    const int jb = blockIdx.x, ib = blockIdx.y;
    const int i0 = ib * BI, j0 = jb * BJ;
    const int tid = threadIdx.x, wid = tid >> 6, lane = tid & 63;
    const int wm = wid >> 2, wn = wid & 3;      // 2x4 wave grid, 64x64 tiles
    const int quad = lane >> 4, l16 = lane & 15;

    floatx4 acc[4][4];
    #pragma unroll
    for (int m = 0; m < 4; ++m)
        #pragma unroll
        for (int n = 0; n < 4; ++n)
            #pragma unroll
            for (int c = 0; c < 4; ++c) acc[m][n][c] = 0.f;

    // staging: wave `wid` owns fragments f = wid*3 .. wid*3+2
    const int lr = lane & 15;
    const int lk = (lane >> 4) * 8;
    const __bf16* src[NSTG];
    #pragma unroll
    for (int c = 0; c < NSTG; ++c) {
        const int f = wid * NSTG + c;
        src[c] = (f < NFRAG_Q)
               ? Qb + (size_t)(i0 + f * 16 + lr) * DIM + lk
               : Ab + (size_t)(j0 + (f - NFRAG_Q) * 16 + lr) * DIM + lk;
    }

    #define STAGE(bufptr, k0)                                                 \
        do {                                                                  \
            _Pragma("unroll")                                                 \
            for (int c = 0; c < NSTG; ++c)                                    \
                ASYNC_COPY16(src[c] + (k0),                                   \
                             (__bf16*)(bufptr) + (wid * NSTG + c) * FRAG_ELEMS); \
        } while (0)

    // rotating buffer pointers (named vars, never runtime-indexed -> regs)
    __bf16* bprev = sbuf[2];   // free at t=0 (prologue stages only 0,1)
    __bf16* bcur  = sbuf[0];
    __bf16* bnext = sbuf[1];

    STAGE(bcur, 0);            // tile 0 -> buf0
    STAGE(bnext, KC);          // tile 1 -> buf1

    for (int t = 0; t < NT; ++t) {
        // single barrier per K-step; counted vmcnt: tile t landed,
        // tile t+1's 3 copies stay in flight.
        if (t < NT - 1) asm volatile("s_waitcnt vmcnt(3)\n\ts_barrier" ::: "memory");
        else            asm volatile("s_waitcnt vmcnt(0)\n\ts_barrier" ::: "memory");

        // STAGE first (T3 recipe): tile t+2 into the buffer read at t-1
        if (t + 2 < NT) STAGE(bprev, (t + 2) * KC);

        const __bf16* cur = bcur;
        bf16x8 qf[4], af[4];
        #pragma unroll
        for (int mf = 0; mf < 4; ++mf)
            qf[mf] = *(const bf16x8*)&cur[(wm * 4 + mf) * FRAG_ELEMS + lane * 8];
        #pragma unroll
        for (int nf = 0; nf < 4; ++nf)
            af[nf] = *(const bf16x8*)&cur[(NFRAG_Q + wn * 4 + nf) * FRAG_ELEMS + lane * 8];

        __builtin_amdgcn_s_setprio(1);
        #pragma unroll
        for (int nf = 0; nf < 4; ++nf)
            #pragma unroll
            for (int mf = 0; mf < 4; ++mf)
                acc[mf][nf] = __builtin_amdgcn_mfma_f32_16x16x32_bf16(
                    qf[mf], af[nf], acc[mf][nf], 0, 0, 0);
        __builtin_amdgcn_s_setprio(0);

        // rotate: {prev,cur,next} <- {cur,next,prev}
        __bf16* tmp = bprev;
        bprev = bcur; bcur = bnext; bnext = tmp;
    }
    #undef STAGE

    // ---- epilogue: (m, l, s, argmax) per row within this wave's 64-col slice
    int cq[4]; float cw[4];
    #pragma unroll
    for (int n = 0; n < 4; ++n) {
        int col = j0 + wn * 64 + n * 16 + l16;
        cq[n] = qid[col];
        cw[n] = w[col];
    }
    const int slice = jb * 4 + wn;             // 0..63

    #pragma unroll
    for (int m = 0; m < 4; ++m) {
        #pragma unroll
        for (int reg = 0; reg < 4; ++reg) {
            const int row = i0 + wm * 64 + m * 16 + quad * 4 + reg;
            const int rq  = qid[row];

            float v[4];
            #pragma unroll
            for (int n = 0; n < 4; ++n) v[n] = acc[m][n][reg] * INV_T;

            // pass 1: slice-wide max
            float pm = fmaxf(fmaxf(v[0], v[1]), fmaxf(v[2], v[3]));
            #pragma unroll
            for (int d = 1; d < 16; d <<= 1)
                pm = fmaxf(pm, __shfl_xor(pm, d, 64));

            // pass 2: local sums against the global max + local argmax
            float ll = __expf(v[0] - pm) + __expf(v[1] - pm) +
                       __expf(v[2] - pm) + __expf(v[3] - pm);
            float ls = 0.f;
            #pragma unroll
            for (int n = 0; n < 4; ++n) ls += (cq[n] == rq) ? cw[n] * v[n] : 0.f;

            float bv = v[0];
            int   bi = j0 + wn * 64 + l16;
            #pragma unroll
            for (int n = 1; n < 4; ++n) {
                int c = j0 + wn * 64 + n * 16 + l16;
                if (v[n] > bv) { bv = v[n]; bi = c; }
            }

            // combined sum + argmax reduce over 16 lanes
            #pragma unroll
            for (int d = 1; d < 16; d <<= 1) {
                ll += __shfl_xor(ll, d, 64);
                ls += __shfl_xor(ls, d, 64);
                float obv = __shfl_xor(bv, d, 64);
                int   obi = __shfl_xor(bi, d, 64);
                if (obv > bv || (obv == bv && obi < bi)) { bv = obv; bi = obi; }
            }
            if (l16 == 0) {
                int idx = row * 64 + slice;
                Pm[idx] = pm; Pl[idx] = ll; Ps[idx] = ls;
                Pbv[idx] = bv; Pbi[idx] = bi;
            }
        }
    }
}

// ---------------------------------------------------------------------------
// Kernel 3: merge 64 slice-partials per row -> loss/acc accumulated into
// out[0..1]. 64 blocks x 1024 threads: each block reduces 64 rows
// (16 waves x 4 rows), combines in LDS, then a SINGLE pair of atomicAdds
// per block (128 same-line atomics total vs 2048 in R7).
// ---------------------------------------------------------------------------
__global__ __launch_bounds__(1024) void row_reduce_kernel(
    const float* __restrict__ Pm, const float* __restrict__ Pl,
    const float* __restrict__ Ps, const float* __restrict__ Pbv,
    const int* __restrict__ Pbi, const int* __restrict__ qid,
    float* __restrict__ out)
{
    const int wv   = threadIdx.x >> 6;   // 0..15
    const int lane = threadIdx.x & 63;

    float s1 = 0.f, s2 = 0.f;
    #pragma unroll
    for (int k = 0; k < 4; ++k) {
        const int r   = blockIdx.x * 64 + wv * 4 + k;
        const int idx = r * 64 + lane;

        float m = Pm[idx], l = Pl[idx], s = Ps[idx], bv = Pbv[idx];
        int   bi = Pbi[idx];

        #pragma unroll
        for (int d = 1; d < 64; d <<= 1) {
            float om  = __shfl_xor(m, d, 64);
            float ol  = __shfl_xor(l, d, 64);
            float os  = __shfl_xor(s, d, 64);
            float obv = __shfl_xor(bv, d, 64);
            int   obi = __shfl_xor(bi, d, 64);
            float nm = fmaxf(m, om);
            l = l * __expf(m - nm) + ol * __expf(om - nm);
            m = nm;
            s += os;
            if (obv > bv || (obv == bv && obi < bi)) { bv = obv; bi = obi; }
        }
        if (lane == 0) {
            s1 += (m + logf(l)) - s;
            s2 += (qid[bi] == qid[r]) ? 1.f : 0.f;
        }
    }

    __shared__ float r1[16], r2[16];
    if (lane == 0) { r1[wv] = s1; r2[wv] = s2; }
    __syncthreads();
    if (threadIdx.x == 0) {
        float t1 = 0.f, t2 = 0.f;
        #pragma unroll
        for (int i = 0; i < 16; ++i) { t1 += r1[i]; t2 += r2[i]; }
        atomicAdd(&out[0], t1 * (1.f / (float)BATCH));
        atomicAdd(&out[1], t2 * (1.f / (float)BATCH));
    }
}

// ---------------------------------------------------------------------------
extern "C" void kernel_launch(void* const* d_in, const int* in_sizes, int n_in,
                              void* d_out, int out_size, void* d_ws, size_t ws_size,
                              hipStream_t stream)
{
    const float* Q      = (const float*)d_in[0];
    const float* A      = (const float*)d_in[1];
    const int*   qid    = (const int*)d_in[2];
    const float* ranks  = (const float*)d_in[3];
    const float* scores = (const float*)d_in[4];
    float* out = (float*)d_out;

    // ws layout: Qb[4M bf16]=8MB | Ab[4M bf16]=8MB | w[4096] |
    //            Pm,Pl,Ps,Pbv[262144] | Pbi[262144]
    __bf16* Qb = (__bf16*)d_ws;
    __bf16* Ab = Qb + (size_t)BATCH * DIM;
    float* w   = (float*)(Ab + (size_t)BATCH * DIM);
    float* Pm  = w + BATCH;
    float* Pl  = Pm + BATCH * 64;
    float* Ps  = Pl + BATCH * 64;
    float* Pbv = Ps + BATCH * 64;
    int*   Pbi = (int*)(Pbv + BATCH * 64);

    prep_kernel<<<1025, 256, 0, stream>>>(Q, A, Qb, Ab, qid, ranks, scores, w, out);

    dim3 grid(BATCH / BJ, BATCH / BI);  // 16 x 32 = 512 blocks
    fused_simloss_kernel<<<grid, 512, 0, stream>>>(Qb, Ab, qid, w, Pm, Pl, Ps, Pbv, Pbi);

    row_reduce_kernel<<<64, 1024, 0, stream>>>(Pm, Pl, Ps, Pbv, Pbi, qid, out);
}